// Round 9
// baseline (332.665 us; speedup 1.0000x reference)
//
#include <hip/hip_runtime.h>
#include <stdint.h>
#include <math.h>

// Problem constants (B,L,H,D fixed by setup_inputs)
#define Bn 4
#define Ln 2048
#define Hn 8
#define Dn 64
#define BHn (Bn*Hn)
#define NTOP 40   // FACTOR * ceil(log(2048)) = 5*8
#define SK   40
#define NSAMP (Ln*SK)        // 81920

// ---------------- Threefry-2x32 (exact JAX replication) ----------------
__host__ __device__ inline uint32_t rotl32(uint32_t x, int r) {
  return (x << r) | (x >> (32 - r));
}

__host__ __device__ inline void tf2x32(uint32_t k0, uint32_t k1,
                                       uint32_t& x0, uint32_t& x1) {
  const uint32_t ks2 = k0 ^ k1 ^ 0x1BD11BDAu;
  const int RA[4] = {13, 15, 26, 6};
  const int RB[4] = {17, 29, 16, 24};
  x0 += k0; x1 += k1;
  for (int i = 0; i < 4; i++) { x0 += x1; x1 = rotl32(x1, RA[i]); x1 ^= x0; }
  x0 += k1;  x1 += ks2 + 1u;
  for (int i = 0; i < 4; i++) { x0 += x1; x1 = rotl32(x1, RB[i]); x1 ^= x0; }
  x0 += ks2; x1 += k0 + 2u;
  for (int i = 0; i < 4; i++) { x0 += x1; x1 = rotl32(x1, RA[i]); x1 ^= x0; }
  x0 += k0;  x1 += k1 + 3u;
  for (int i = 0; i < 4; i++) { x0 += x1; x1 = rotl32(x1, RB[i]); x1 ^= x0; }
  x0 += k1;  x1 += ks2 + 4u;
  for (int i = 0; i < 4; i++) { x0 += x1; x1 = rotl32(x1, RA[i]); x1 ^= x0; }
  x0 += ks2; x1 += k0 + 5u;
}

// jax_threefry_partitionable=True: elem n -> ctr (0, n); draw = out0 ^ out1
__device__ inline int draw2048(uint32_t k0, uint32_t k1, uint32_t n) {
  uint32_t a = 0u, b = n;
  tf2x32(k0, k1, a, b);
  return (int)((a ^ b) & (Ln - 1));
}

// ---------------- DPP 16-lane sum reduce (VALU pipe, zero DS ops) ----------------
template<int CTRL>
__device__ __forceinline__ float dpp_add(float x) {
  int y = __builtin_amdgcn_update_dpp(0, __float_as_int(x), CTRL, 0xF, 0xF, true);
  return x + __int_as_float(y);
}
__device__ __forceinline__ float red16(float d) {
  d = dpp_add<0xB1>(d);   // quad_perm [1,0,3,2]  (xor 1)
  d = dpp_add<0x4E>(d);   // quad_perm [2,3,0,1]  (xor 2)
  d = dpp_add<0x141>(d);  // row_half_mirror      (pairs across 8-halves)
  d = dpp_add<0x140>(d);  // row_mirror           (pairs across 16-row)
  return d;
}

// ---------------- fused launch 1: vsum_partial (blocks 0..1023) +
//                  compute_M v4 (blocks 1024..9215) ----------------
// v4 = best-measured variant (R7). v5's full 20-load pre-issue (R8) regressed
// ~2 us (occupancy loss from 80 live load VGPRs) -> reverted to depth-1 group
// prefetch. compute_M is near its L2-random-gather roofline; leave it.
__global__ __launch_bounds__(256) void fused_m_vsum(const float* __restrict__ Q,
                                                    const float* __restrict__ K,
                                                    const float* __restrict__ V,
                                                    float* __restrict__ M,
                                                    float* __restrict__ partial,
                                                    uint32_t k0, uint32_t k1) {
  __shared__ alignas(16) int sidx[8][40];    // compute_M path (1.25 KB)
  __shared__ float red[4][64];               // vsum path (1 KB)

  if (blockIdx.x < 1024) {
    // ---- vsum_partial: per-tile (64 l) V sums ----
    int bid  = blockIdx.x;
    int tile = bid & 31;
    int bh   = bid >> 5;
    int d = threadIdx.x & 63;
    int g = threadIdx.x >> 6;
    const float* Vb = V + (size_t)bh * Ln * Dn;
    int l0 = tile * 64 + g * 16;
    float s = 0.f;
    for (int j = 0; j < 16; j++) s += Vb[(size_t)(l0 + j) * Dn + d];
    red[g][d] = s;
    __syncthreads();
    if (g == 0)
      partial[((size_t)bh * 32 + tile) * 64 + d] =
          red[0][d] + red[1][d] + red[2][d] + red[3][d];
    return;
  }

  int cmb = blockIdx.x - 1024;        // 0..8191; 1024%8==0 keeps xcd mapping
  int xcd = cmb & 7;
  int idx = cmb >> 3;                 // 0..1023
  int bh  = (idx & 3) * 8 + xcd;      // {xcd, xcd+8, xcd+16, xcd+24}
  int seg = idx >> 2;                 // 0..255
  int tid = threadIdx.x;
  int q   = tid >> 5;                 // query slot in wg: 0..7
  int h   = tid & 31;                 // lane within half-wave
  int j   = h & 15;                   // float4 slot within row
  int p   = h >> 4;                   // sample-half: samples [p*20, p*20+20)
  int i   = seg * 8 + q;              // query index

  // index gen: thread (q, l=h) draws sample l; l<8 also draws 32+l
  {
    uint32_t n0 = (uint32_t)(i * SK);
    sidx[q][h] = draw2048(k0, k1, n0 + h);
    if (h < 8) sidx[q][32 + h] = draw2048(k0, k1, n0 + 32 + h);
  }

  const float* Qb = Q + ((size_t)bh * Ln + i) * Dn;
  float4 qf = ((const float4*)Qb)[j];
  __syncthreads();

  // this half's 20 indices (5 int4 groups; p*20*4B = 80B, 16B-aligned)
  int4 I[5];
#pragma unroll
  for (int t = 0; t < 5; t++) I[t] = *(const int4*)&sidx[q][p * 20 + t * 4];

  const float* Kb = K + (size_t)bh * Ln * Dn;
  float mx = -INFINITY, sm = 0.f;

  float4 kf[4], kn[4];
  {
    int ls[4] = {I[0].x, I[0].y, I[0].z, I[0].w};
#pragma unroll
    for (int c = 0; c < 4; c++)
      kf[c] = ((const float4*)(Kb + (size_t)ls[c] * Dn))[j];
  }
#pragma unroll
  for (int t = 0; t < 5; t++) {
    if (t < 4) {                       // depth-1 group prefetch (8 in flight)
      int ls[4] = {I[t + 1].x, I[t + 1].y, I[t + 1].z, I[t + 1].w};
#pragma unroll
      for (int c = 0; c < 4; c++)
        kn[c] = ((const float4*)(Kb + (size_t)ls[c] * Dn))[j];
    }
#pragma unroll
    for (int c = 0; c < 4; c++) {
      float d = qf.x * kf[c].x + qf.y * kf[c].y + qf.z * kf[c].z + qf.w * kf[c].w;
      d = red16(d);                    // full 64-elem dot in every lane
      mx = fmaxf(mx, d);
      sm += d;
    }
    if (t < 4) {
#pragma unroll
      for (int c = 0; c < 4; c++) kf[c] = kn[c];
    }
  }
  // merge the two 20-sample halves (stays within the 32-lane half-wave)
  mx = fmaxf(mx, __shfl_xor(mx, 16, 64));
  sm += __shfl_xor(sm, 16, 64);
  if (h == 0)
    M[(size_t)bh * Ln + i] = mx - sm * (1.0f / (float)Ln);
}

// ---------------- launch 2: unordered exact top-40 via bisection select ----------------
// (proven R6/R7/R8)
__global__ __launch_bounds__(256) void topk_select(const float* __restrict__ M,
                                                   int* __restrict__ Mtop) {
  int bh = blockIdx.x;
  int tid = threadIdx.x;
  const float* m = M + (size_t)bh * Ln;

  // 8 contiguous values per thread (2x dwordx4), monotonic keys
  uint32_t k[8]; int li[8];
  float4 va = ((const float4*)m)[tid * 2];
  float4 vb = ((const float4*)m)[tid * 2 + 1];
  float vals[8] = {va.x, va.y, va.z, va.w, vb.x, vb.y, vb.z, vb.w};
#pragma unroll
  for (int j = 0; j < 8; j++) {
    uint32_t u = __float_as_uint(vals[j]);
    k[j] = (u & 0x80000000u) ? ~u : (u | 0x80000000u);
    li[j] = tid * 8 + j;
  }

  __shared__ int cnts[32];
  __shared__ int cA, outc, eqn2;
  __shared__ int eqbuf[2048];
  if (tid < 32) cnts[tid] = 0;
  if (tid == 0) { cA = 0; outc = 0; eqn2 = 0; }
  __syncthreads();

  // find K40 = max T with count(key >= T) >= NTOP
  uint32_t lo = 0u, hi = 0xFFFFFFFFu;
  for (int it = 0; it < 32; ++it) {
    if (lo >= hi) break;                       // uniform across block
    uint32_t mid = lo + ((hi - lo) >> 1) + 1u; // in (lo, hi], no overflow
    int cw = 0;
#pragma unroll
    for (int j = 0; j < 8; j++)
      cw += __popcll(__ballot(k[j] >= mid));
    if ((tid & 63) == 0) atomicAdd(&cnts[it], cw);
    __syncthreads();
    int total = cnts[it];
    if (total >= NTOP) lo = mid; else hi = mid - 1u;
  }
  uint32_t K40 = lo;

  // count strictly-above
  {
    int cw = 0;
#pragma unroll
    for (int j = 0; j < 8; j++)
      cw += __popcll(__ballot(k[j] > K40));
    if ((tid & 63) == 0) atomicAdd(&cA, cw);
  }
  __syncthreads();

  // compact: strictly-greater (any order), ties into eqbuf
#pragma unroll
  for (int j = 0; j < 8; j++) {
    if (k[j] > K40) {
      int p = atomicAdd(&outc, 1);
      Mtop[bh * NTOP + p] = li[j];
    } else if (k[j] == K40) {
      int p = atomicAdd(&eqn2, 1);
      eqbuf[p] = li[j];
    }
  }
  __syncthreads();

  if (tid == 0) {
    int need = NTOP - cA;        // >= 1 by construction of K40
    int n = eqn2;
    for (int s = 0; s < need; s++) {   // typically need==1, n==1
      int best = 0x7fffffff, bi = 0;
      for (int t = 0; t < n; t++)
        if (eqbuf[t] < best) { best = eqbuf[t]; bi = t; }
      Mtop[bh * NTOP + cA + s] = best;
      eqbuf[bi] = 0x7fffffff;
    }
  }
}

// ---------------- launch 3: sparse attention (blocks 0..639, UC=2 x 20 chunks)
//                  + context_write (blocks 640..895) ----------------
// R8 counters: sparse at 59 us with VALU 22% / occ 19% -- after ctx's 256
// blocks drain, each CU holds ONE sparse block (2 waves/SIMD) and pass 1/3 L2
// latency is exposed. UC is the one safe lever on this spill-fragile kernel
// (pure parameter: acc[UC][4] shrinks 20->8 regs, sc[UC][Ln] 40->16 KB; the
// proven pass structure is untouched). UC=2 -> 640 sparse blocks, LDS ~24 KB,
// 4 blocks/CU resident -> ~5 waves/SIMD steady state (2.5x latency hiding).
// Cost: K+Q streamed per-block -> 2.5x L2 stream volume (L2/L3-resident, not
// HBM). Tripwire: WRITE_SIZE ~21 MB; >>25 MB means spill returned.
#define UC 2
#define NCHUNK 20
#define SPB 640
__global__ __launch_bounds__(512, 2) void sparse_ctx(const float* __restrict__ Q,
                                                     const float* __restrict__ K,
                                                     const float* __restrict__ V,
                                                     const int* __restrict__ Mtop,
                                                     const float* __restrict__ partial,
                                                     float* __restrict__ out) {
  __shared__ alignas(16) float sc[UC][Ln];           // 16 KB scores->probs
  __shared__ alignas(16) float qs[UC][Dn];
  __shared__ alignas(16) float ks[UC][Dn];
  __shared__ float vs[UC][Dn];
  __shared__ alignas(16) float redp[8][UC][64];      // 4 KB partial attn@V
  __shared__ int   rows_s[UC];
  __shared__ float inv_s[UC];
  __shared__ alignas(16) float credR[8][64];         // ctx path (2 KB)
  __shared__ uint32_t cmask[64];                     // ctx path: selected-row bits

  if (blockIdx.x >= SPB) {
    // ---- context_write: prefix + cumsum + transposed write, skip selected ----
    // (verbatim R8: 256 blocks, 256-l tiles via two 128-l passes)
    int bid = blockIdx.x - SPB;      // 0..255
    int bh  = bid >> 3;              // 0..31
    int T   = bid & 7;               // 256-l tile
    int b = bh >> 3, h = bh & 7;
    int tid = threadIdx.x, d = tid & 63, g = tid >> 6;   // g 0..7
    if (tid < 64) cmask[tid] = 0u;
    __syncthreads();
    if (tid < NTOP) {
      int r = Mtop[bh * NTOP + tid];
      atomicOr(&cmask[r >> 5], 1u << (r & 31));
    }
    float p = 0.f;
    for (int t = g; t < 4 * T; t += 8)
      p += partial[((size_t)bh * 32 + t) * 64 + d];
    credR[g][d] = p;
    __syncthreads();                 // also fences cmask population
    float prefix = 0.f;
#pragma unroll
    for (int gg = 0; gg < 8; gg++) prefix += credR[gg][d];
    __syncthreads();
    const float* Vb = V + (size_t)bh * Ln * Dn;
#pragma unroll
    for (int pass = 0; pass < 2; pass++) {
      int l0 = T * 256 + pass * 128 + g * 16;
      float vloc[16]; float s = 0.f;
      for (int j = 0; j < 16; j++) {
        vloc[j] = Vb[(size_t)(l0 + j) * Dn + d];
        s += vloc[j];
      }
      credR[g][d] = s;
      __syncthreads();
      float running = prefix;
      for (int gg = 0; gg < g; gg++) running += credR[gg][d];
      for (int j = 0; j < 16; j++) {
        int l = l0 + j;
        running += vloc[j];
        if (!((cmask[l >> 5] >> (l & 31)) & 1u))
          out[(((size_t)b * Ln + l) * Hn + h) * Dn + d] =
              0.5f * ((float)(l + 1) * vloc[j] + running);
      }
      if (pass == 0) {
        float all8 = 0.f;
#pragma unroll
        for (int gg = 0; gg < 8; gg++) all8 += credR[gg][d];
        prefix += all8;
        __syncthreads();             // credR reused next pass
      }
    }
    return;
  }

  // ---- sparse attention over UC selected rows (proven pass structure) ----
  int xcd  = blockIdx.x & 7;
  int rest = blockIdx.x >> 3;       // 0..79
  int chunk = rest % NCHUNK;        // 0..19
  int bh    = (rest / NCHUNK) * 8 + xcd;
  int b = bh >> 3, h = bh & 7;
  const float* Qb = Q + (size_t)bh * Ln * Dn;
  const float* Kb = K + (size_t)bh * Ln * Dn;
  const float* Vb = V + (size_t)bh * Ln * Dn;
  int tid = threadIdx.x;

  if (tid < UC * 64) {
    int u = tid >> 6, d = tid & 63;
    int row = Mtop[bh * NTOP + chunk * UC + u];
    if (d == 0) rows_s[u] = row;
    qs[u][d] = Qb[(size_t)row * Dn + d];
    ks[u][d] = Kb[(size_t)row * Dn + d];
    vs[u][d] = Vb[(size_t)row * Dn + d];
  }
  __syncthreads();

  // pass 1: scores[u][l] = 0.0625*(Qsel[u].K[l] + Q[l].Ksel[u]), causal mask l>row
  float acc[UC][4];
#pragma unroll
  for (int u = 0; u < UC; u++)
#pragma unroll
    for (int j = 0; j < 4; j++) acc[u][j] = 0.f;

  for (int tt = 0; tt < 4; tt++) {
    float4 kk[4][4], qq[4][4];    // [j][ts] — 32 loads issued before use
#pragma unroll
    for (int j = 0; j < 4; j++) {
      int l = tid + j * 512;
      const float4* kp = (const float4*)(Kb + (size_t)l * Dn) + tt * 4;
      const float4* qp = (const float4*)(Qb + (size_t)l * Dn) + tt * 4;
#pragma unroll
      for (int ts = 0; ts < 4; ts++) { kk[j][ts] = kp[ts]; qq[j][ts] = qp[ts]; }
    }
#pragma unroll
    for (int ts = 0; ts < 4; ts++) {
      int t = tt * 4 + ts;
#pragma unroll
      for (int u = 0; u < UC; u++) {
        float4 q4 = *(const float4*)(&qs[u][t * 4]);
        float4 k4 = *(const float4*)(&ks[u][t * 4]);
#pragma unroll
        for (int j = 0; j < 4; j++) {
          acc[u][j] += q4.x * kk[j][ts].x + q4.y * kk[j][ts].y
                     + q4.z * kk[j][ts].z + q4.w * kk[j][ts].w
                     + k4.x * qq[j][ts].x + k4.y * qq[j][ts].y
                     + k4.z * qq[j][ts].z + k4.w * qq[j][ts].w;
        }
      }
    }
  }
#pragma unroll
  for (int u = 0; u < UC; u++) {
    int row = rows_s[u];
#pragma unroll
    for (int j = 0; j < 4; j++) {
      int l = tid + j * 512;
      sc[u][l] = (l > row) ? -1e9f : acc[u][j] * 0.0625f;
    }
  }
  __syncthreads();

  // pass 2: softmax per u; wave w handles u=w (waves 0..UC-1)
  int w = tid >> 6, lane = tid & 63;
  if (w < UC) {
    float mx = -INFINITY;
    for (int kq = 0; kq < 32; kq++) mx = fmaxf(mx, sc[w][lane + 64 * kq]);
    for (int off = 32; off; off >>= 1) mx = fmaxf(mx, __shfl_xor(mx, off, 64));
    float sum = 0.f;
    for (int kq = 0; kq < 32; kq++) {
      float e = __expf(sc[w][lane + 64 * kq] - mx);
      sc[w][lane + 64 * kq] = e;
      sum += e;
    }
    for (int off = 32; off; off >>= 1) sum += __shfl_xor(sum, off, 64);
    if (lane == 0) inv_s[w] = 1.0f / sum;
  }
  __syncthreads();

  // pass 3: attn @ V ; wave w owns l in [w*256, w*256+256) for ALL UC u.
  {
    int quad = lane & 15, lr = lane >> 4;
    int l0w = w * 256;
    const float4* V4 = (const float4*)Vb;
    float4 a[UC];
#pragma unroll
    for (int u = 0; u < UC; u++) a[u] = make_float4(0.f, 0.f, 0.f, 0.f);
    for (int it4 = 0; it4 < 16; it4++) {
      int lb = l0w + lr + it4 * 16;
      float4 v0 = V4[(size_t)(lb)      * 16 + quad];
      float4 v1 = V4[(size_t)(lb + 4)  * 16 + quad];
      float4 v2 = V4[(size_t)(lb + 8)  * 16 + quad];
      float4 v3 = V4[(size_t)(lb + 12) * 16 + quad];
#pragma unroll
      for (int u = 0; u < UC; u++) {
        float s0 = sc[u][lb], s1 = sc[u][lb + 4], s2 = sc[u][lb + 8], s3 = sc[u][lb + 12];
        a[u].x += s0 * v0.x + s1 * v1.x + s2 * v2.x + s3 * v3.x;
        a[u].y += s0 * v0.y + s1 * v1.y + s2 * v2.y + s3 * v3.y;
        a[u].z += s0 * v0.z + s1 * v1.z + s2 * v2.z + s3 * v3.z;
        a[u].w += s0 * v0.w + s1 * v1.w + s2 * v2.w + s3 * v3.w;
      }
    }
#pragma unroll
    for (int u = 0; u < UC; u++) {
#pragma unroll
      for (int off = 16; off < 64; off <<= 1) {
        a[u].x += __shfl_xor(a[u].x, off, 64);
        a[u].y += __shfl_xor(a[u].y, off, 64);
        a[u].z += __shfl_xor(a[u].z, off, 64);
        a[u].w += __shfl_xor(a[u].w, off, 64);
      }
      if (lr == 0) *(float4*)(&redp[w][u][quad * 4]) = a[u];
    }
  }
  __syncthreads();

  if (w < UC) {
    float r = 0.f;
#pragma unroll
    for (int g = 0; g < 8; g++) r += redp[g][w][lane];
    float outv = 0.5f * (vs[w][lane] + r * inv_s[w]);
    int row = rows_s[w];
    out[(((size_t)b * Ln + row) * Hn + h) * Dn + lane] = outv;
  }
}

extern "C" void kernel_launch(void* const* d_in, const int* in_sizes, int n_in,
                              void* d_out, int out_size, void* d_ws, size_t ws_size,
                              hipStream_t stream) {
  const float* Q = (const float*)d_in[0];  // (B,L,H,D) flat == (B,H,L,D) reshape
  const float* K = (const float*)d_in[1];
  const float* V = (const float*)d_in[2];
  float* out = (float*)d_out;
  char* ws = (char*)d_ws;

  float* M       = (float*)(ws + NSAMP * 4);                       // 256 KB
  int*   Mtop    = (int*)(ws + NSAMP * 4 + BHn * Ln * 4);          // 5 KB
  float* partial = (float*)(ws + NSAMP * 4 + BHn * Ln * 4 + BHn * NTOP * 4); // 256 KB

  // Partitionable threefry split of key(42) = (0,42): k2 = tf(key, ctr=(0,1)).
  uint32_t s0 = 0u, s1 = 1u;
  tf2x32(0u, 42u, s0, s1);

  // 3 launches: {vsum || compute_M} -> topk_select -> {sparse_attn || context}
  fused_m_vsum<<<1024 + 8192, 256, 0, stream>>>(Q, K, V, M, partial, s0, s1);
  topk_select<<<BHn, 256, 0, stream>>>(M, Mtop);
  sparse_ctx<<<SPB + 256, 512, 0, stream>>>(Q, K, V, Mtop, partial, out);
}

// Round 10
// 174.060 us; speedup vs baseline: 1.9112x; 1.9112x over previous
//
#include <hip/hip_runtime.h>
#include <stdint.h>
#include <math.h>

// Problem constants (B,L,H,D fixed by setup_inputs)
#define Bn 4
#define Ln 2048
#define Hn 8
#define Dn 64
#define BHn (Bn*Hn)
#define NTOP 40   // FACTOR * ceil(log(2048)) = 5*8
#define SK   40
#define NSAMP (Ln*SK)        // 81920

// ---------------- Threefry-2x32 (exact JAX replication) ----------------
__host__ __device__ inline uint32_t rotl32(uint32_t x, int r) {
  return (x << r) | (x >> (32 - r));
}

__host__ __device__ inline void tf2x32(uint32_t k0, uint32_t k1,
                                       uint32_t& x0, uint32_t& x1) {
  const uint32_t ks2 = k0 ^ k1 ^ 0x1BD11BDAu;
  const int RA[4] = {13, 15, 26, 6};
  const int RB[4] = {17, 29, 16, 24};
  x0 += k0; x1 += k1;
  for (int i = 0; i < 4; i++) { x0 += x1; x1 = rotl32(x1, RA[i]); x1 ^= x0; }
  x0 += k1;  x1 += ks2 + 1u;
  for (int i = 0; i < 4; i++) { x0 += x1; x1 = rotl32(x1, RB[i]); x1 ^= x0; }
  x0 += ks2; x1 += k0 + 2u;
  for (int i = 0; i < 4; i++) { x0 += x1; x1 = rotl32(x1, RA[i]); x1 ^= x0; }
  x0 += k0;  x1 += k1 + 3u;
  for (int i = 0; i < 4; i++) { x0 += x1; x1 = rotl32(x1, RB[i]); x1 ^= x0; }
  x0 += k1;  x1 += ks2 + 4u;
  for (int i = 0; i < 4; i++) { x0 += x1; x1 = rotl32(x1, RA[i]); x1 ^= x0; }
  x0 += ks2; x1 += k0 + 5u;
}

// jax_threefry_partitionable=True: elem n -> ctr (0, n); draw = out0 ^ out1
__device__ inline int draw2048(uint32_t k0, uint32_t k1, uint32_t n) {
  uint32_t a = 0u, b = n;
  tf2x32(k0, k1, a, b);
  return (int)((a ^ b) & (Ln - 1));
}

// ---------------- DPP 16-lane sum reduce (VALU pipe, zero DS ops) ----------------
template<int CTRL>
__device__ __forceinline__ float dpp_add(float x) {
  int y = __builtin_amdgcn_update_dpp(0, __float_as_int(x), CTRL, 0xF, 0xF, true);
  return x + __int_as_float(y);
}
__device__ __forceinline__ float red16(float d) {
  d = dpp_add<0xB1>(d);   // quad_perm [1,0,3,2]  (xor 1)
  d = dpp_add<0x4E>(d);   // quad_perm [2,3,0,1]  (xor 2)
  d = dpp_add<0x141>(d);  // row_half_mirror      (pairs across 8-halves)
  d = dpp_add<0x140>(d);  // row_mirror           (pairs across 16-row)
  return d;
}

// ---------------- fused launch 1: vsum_partial (blocks 0..1023) +
//                  compute_M v6 (blocks 1024..9215) ----------------
// v6 = v4 (best-measured) + L2-locality block remap. Diagnosis: the gather is
// L3-BW-bound, not latency-bound (v4 chain-halving and v5 MLP both null; 671
// MB / ~14 TB/s L3 ~= measured time). Old mapping bh=(idx&3)*8+xcd cycled 4
// different 4 MB K panels every 4 consecutive blocks -> 16 MB active set per
// XCD vs 4 MB L2 -> all gathers miss to L3. New mapping bh=xcd+8*(idx>>8):
// each XCD's 1024 blocks process its 4 panels SEQUENTIALLY (256 blocks per
// panel), active set ~= one 4 MB panel -> gathers hit L2 (34.5 TB/s).
// Threefry draws and M values bit-identical (only block->query map changes).
__global__ __launch_bounds__(256) void fused_m_vsum(const float* __restrict__ Q,
                                                    const float* __restrict__ K,
                                                    const float* __restrict__ V,
                                                    float* __restrict__ M,
                                                    float* __restrict__ partial,
                                                    uint32_t k0, uint32_t k1) {
  __shared__ alignas(16) int sidx[8][40];    // compute_M path (1.25 KB)
  __shared__ float red[4][64];               // vsum path (1 KB)

  if (blockIdx.x < 1024) {
    // ---- vsum_partial: per-tile (64 l) V sums ----
    int bid  = blockIdx.x;
    int tile = bid & 31;
    int bh   = bid >> 5;
    int d = threadIdx.x & 63;
    int g = threadIdx.x >> 6;
    const float* Vb = V + (size_t)bh * Ln * Dn;
    int l0 = tile * 64 + g * 16;
    float s = 0.f;
    for (int j = 0; j < 16; j++) s += Vb[(size_t)(l0 + j) * Dn + d];
    red[g][d] = s;
    __syncthreads();
    if (g == 0)
      partial[((size_t)bh * 32 + tile) * 64 + d] =
          red[0][d] + red[1][d] + red[2][d] + red[3][d];
    return;
  }

  int cmb = blockIdx.x - 1024;        // 0..8191; 1024%8==0 keeps xcd mapping
  int xcd = cmb & 7;
  int idx = cmb >> 3;                 // 0..1023
  int bh  = xcd + 8 * (idx >> 8);     // 256 consecutive blocks share ONE panel
  int seg = idx & 255;                // 0..255
  int tid = threadIdx.x;
  int q   = tid >> 5;                 // query slot in wg: 0..7
  int h   = tid & 31;                 // lane within half-wave
  int j   = h & 15;                   // float4 slot within row
  int p   = h >> 4;                   // sample-half: samples [p*20, p*20+20)
  int i   = seg * 8 + q;              // query index

  // index gen: thread (q, l=h) draws sample l; l<8 also draws 32+l
  {
    uint32_t n0 = (uint32_t)(i * SK);
    sidx[q][h] = draw2048(k0, k1, n0 + h);
    if (h < 8) sidx[q][32 + h] = draw2048(k0, k1, n0 + 32 + h);
  }

  const float* Qb = Q + ((size_t)bh * Ln + i) * Dn;
  float4 qf = ((const float4*)Qb)[j];
  __syncthreads();

  // this half's 20 indices (5 int4 groups; p*20*4B = 80B, 16B-aligned)
  int4 I[5];
#pragma unroll
  for (int t = 0; t < 5; t++) I[t] = *(const int4*)&sidx[q][p * 20 + t * 4];

  const float* Kb = K + (size_t)bh * Ln * Dn;
  float mx = -INFINITY, sm = 0.f;

  float4 kf[4], kn[4];
  {
    int ls[4] = {I[0].x, I[0].y, I[0].z, I[0].w};
#pragma unroll
    for (int c = 0; c < 4; c++)
      kf[c] = ((const float4*)(Kb + (size_t)ls[c] * Dn))[j];
  }
#pragma unroll
  for (int t = 0; t < 5; t++) {
    if (t < 4) {                       // depth-1 group prefetch (8 in flight)
      int ls[4] = {I[t + 1].x, I[t + 1].y, I[t + 1].z, I[t + 1].w};
#pragma unroll
      for (int c = 0; c < 4; c++)
        kn[c] = ((const float4*)(Kb + (size_t)ls[c] * Dn))[j];
    }
#pragma unroll
    for (int c = 0; c < 4; c++) {
      float d = qf.x * kf[c].x + qf.y * kf[c].y + qf.z * kf[c].z + qf.w * kf[c].w;
      d = red16(d);                    // full 64-elem dot in every lane
      mx = fmaxf(mx, d);
      sm += d;
    }
    if (t < 4) {
#pragma unroll
      for (int c = 0; c < 4; c++) kf[c] = kn[c];
    }
  }
  // merge the two 20-sample halves (stays within the 32-lane half-wave)
  mx = fmaxf(mx, __shfl_xor(mx, 16, 64));
  sm += __shfl_xor(sm, 16, 64);
  if (h == 0)
    M[(size_t)bh * Ln + i] = mx - sm * (1.0f / (float)Ln);
}

// ---------------- launch 2: unordered exact top-40 via bisection select ----------------
// (proven R6-R9)
__global__ __launch_bounds__(256) void topk_select(const float* __restrict__ M,
                                                   int* __restrict__ Mtop) {
  int bh = blockIdx.x;
  int tid = threadIdx.x;
  const float* m = M + (size_t)bh * Ln;

  // 8 contiguous values per thread (2x dwordx4), monotonic keys
  uint32_t k[8]; int li[8];
  float4 va = ((const float4*)m)[tid * 2];
  float4 vb = ((const float4*)m)[tid * 2 + 1];
  float vals[8] = {va.x, va.y, va.z, va.w, vb.x, vb.y, vb.z, vb.w};
#pragma unroll
  for (int j = 0; j < 8; j++) {
    uint32_t u = __float_as_uint(vals[j]);
    k[j] = (u & 0x80000000u) ? ~u : (u | 0x80000000u);
    li[j] = tid * 8 + j;
  }

  __shared__ int cnts[32];
  __shared__ int cA, outc, eqn2;
  __shared__ int eqbuf[2048];
  if (tid < 32) cnts[tid] = 0;
  if (tid == 0) { cA = 0; outc = 0; eqn2 = 0; }
  __syncthreads();

  // find K40 = max T with count(key >= T) >= NTOP
  uint32_t lo = 0u, hi = 0xFFFFFFFFu;
  for (int it = 0; it < 32; ++it) {
    if (lo >= hi) break;                       // uniform across block
    uint32_t mid = lo + ((hi - lo) >> 1) + 1u; // in (lo, hi], no overflow
    int cw = 0;
#pragma unroll
    for (int j = 0; j < 8; j++)
      cw += __popcll(__ballot(k[j] >= mid));
    if ((tid & 63) == 0) atomicAdd(&cnts[it], cw);
    __syncthreads();
    int total = cnts[it];
    if (total >= NTOP) lo = mid; else hi = mid - 1u;
  }
  uint32_t K40 = lo;

  // count strictly-above
  {
    int cw = 0;
#pragma unroll
    for (int j = 0; j < 8; j++)
      cw += __popcll(__ballot(k[j] > K40));
    if ((tid & 63) == 0) atomicAdd(&cA, cw);
  }
  __syncthreads();

  // compact: strictly-greater (any order), ties into eqbuf
#pragma unroll
  for (int j = 0; j < 8; j++) {
    if (k[j] > K40) {
      int p = atomicAdd(&outc, 1);
      Mtop[bh * NTOP + p] = li[j];
    } else if (k[j] == K40) {
      int p = atomicAdd(&eqn2, 1);
      eqbuf[p] = li[j];
    }
  }
  __syncthreads();

  if (tid == 0) {
    int need = NTOP - cA;        // >= 1 by construction of K40
    int n = eqn2;
    for (int s = 0; s < need; s++) {   // typically need==1, n==1
      int best = 0x7fffffff, bi = 0;
      for (int t = 0; t < n; t++)
        if (eqbuf[t] < best) { best = eqbuf[t]; bi = t; }
      Mtop[bh * NTOP + cA + s] = best;
      eqbuf[bi] = 0x7fffffff;
    }
  }
}

// ---------------- launch 3: sparse attention (blocks 0..255, VERBATIM R8-proven)
//                  + context_write (blocks 256..511, 256-l tiles) ----------------
// FROZEN at the R8 source (59.1 us, WRITE 21 MB). Four structural perturbations
// (R1 fragments, R3 1024-thr, R9 UC=2) each tripped a hipcc scratch-spill cliff
// (160-310 MB WRITE). R9's spill was exactly 512 B/thread = the kk/qq prefetch
// block dumped to scratch. Do NOT touch this kernel.
#define UC 5
#define SPB 256
__global__ __launch_bounds__(512, 2) void sparse_ctx(const float* __restrict__ Q,
                                                     const float* __restrict__ K,
                                                     const float* __restrict__ V,
                                                     const int* __restrict__ Mtop,
                                                     const float* __restrict__ partial,
                                                     float* __restrict__ out) {
  __shared__ alignas(16) float sc[UC][Ln];           // 40 KB scores->probs
  __shared__ alignas(16) float qs[UC][Dn];
  __shared__ alignas(16) float ks[UC][Dn];
  __shared__ float vs[UC][Dn];
  __shared__ alignas(16) float redp[8][UC][64];      // 10 KB partial attn@V
  __shared__ int   rows_s[UC];
  __shared__ float inv_s[UC];
  __shared__ alignas(16) float credR[8][64];         // ctx path (2 KB)
  __shared__ uint32_t cmask[64];                     // ctx path: selected-row bits

  if (blockIdx.x >= SPB) {
    // ---- context_write: prefix + cumsum + transposed write, skip selected ----
    int bid = blockIdx.x - SPB;      // 0..255
    int bh  = bid >> 3;              // 0..31
    int T   = bid & 7;               // 256-l tile
    int b = bh >> 3, h = bh & 7;
    int tid = threadIdx.x, d = tid & 63, g = tid >> 6;   // g 0..7
    if (tid < 64) cmask[tid] = 0u;
    __syncthreads();
    if (tid < NTOP) {
      int r = Mtop[bh * NTOP + tid];
      atomicOr(&cmask[r >> 5], 1u << (r & 31));
    }
    float p = 0.f;
    for (int t = g; t < 4 * T; t += 8)
      p += partial[((size_t)bh * 32 + t) * 64 + d];
    credR[g][d] = p;
    __syncthreads();                 // also fences cmask population
    float prefix = 0.f;
#pragma unroll
    for (int gg = 0; gg < 8; gg++) prefix += credR[gg][d];
    __syncthreads();
    const float* Vb = V + (size_t)bh * Ln * Dn;
#pragma unroll
    for (int pass = 0; pass < 2; pass++) {
      int l0 = T * 256 + pass * 128 + g * 16;
      float vloc[16]; float s = 0.f;
      for (int j = 0; j < 16; j++) {
        vloc[j] = Vb[(size_t)(l0 + j) * Dn + d];
        s += vloc[j];
      }
      credR[g][d] = s;
      __syncthreads();
      float running = prefix;
      for (int gg = 0; gg < g; gg++) running += credR[gg][d];
      for (int j = 0; j < 16; j++) {
        int l = l0 + j;
        running += vloc[j];
        if (!((cmask[l >> 5] >> (l & 31)) & 1u))
          out[(((size_t)b * Ln + l) * Hn + h) * Dn + d] =
              0.5f * ((float)(l + 1) * vloc[j] + running);
      }
      if (pass == 0) {
        float all8 = 0.f;
#pragma unroll
        for (int gg = 0; gg < 8; gg++) all8 += credR[gg][d];
        prefix += all8;
        __syncthreads();             // credR reused next pass
      }
    }
    return;
  }

  // ---- sparse attention over 5 selected rows (VERBATIM R5-R8) ----
  int xcd  = blockIdx.x & 7;
  int rest = blockIdx.x >> 3;     // 0..31
  int chunk = rest & 7;
  int bh    = (rest >> 3) * 8 + xcd;
  int b = bh >> 3, h = bh & 7;
  const float* Qb = Q + (size_t)bh * Ln * Dn;
  const float* Kb = K + (size_t)bh * Ln * Dn;
  const float* Vb = V + (size_t)bh * Ln * Dn;
  int tid = threadIdx.x;

  if (tid < UC * 64) {
    int u = tid >> 6, d = tid & 63;
    int row = Mtop[bh * NTOP + chunk * UC + u];
    if (d == 0) rows_s[u] = row;
    qs[u][d] = Qb[(size_t)row * Dn + d];
    ks[u][d] = Kb[(size_t)row * Dn + d];
    vs[u][d] = Vb[(size_t)row * Dn + d];
  }
  __syncthreads();

  // pass 1: scores[u][l] = 0.0625*(Qsel[u].K[l] + Q[l].Ksel[u]), causal mask l>row
  float acc[UC][4];
#pragma unroll
  for (int u = 0; u < UC; u++)
#pragma unroll
    for (int j = 0; j < 4; j++) acc[u][j] = 0.f;

  for (int tt = 0; tt < 4; tt++) {
    float4 kk[4][4], qq[4][4];    // [j][ts] — 32 loads issued before use
#pragma unroll
    for (int j = 0; j < 4; j++) {
      int l = tid + j * 512;
      const float4* kp = (const float4*)(Kb + (size_t)l * Dn) + tt * 4;
      const float4* qp = (const float4*)(Qb + (size_t)l * Dn) + tt * 4;
#pragma unroll
      for (int ts = 0; ts < 4; ts++) { kk[j][ts] = kp[ts]; qq[j][ts] = qp[ts]; }
    }
#pragma unroll
    for (int ts = 0; ts < 4; ts++) {
      int t = tt * 4 + ts;
#pragma unroll
      for (int u = 0; u < UC; u++) {
        float4 q4 = *(const float4*)(&qs[u][t * 4]);
        float4 k4 = *(const float4*)(&ks[u][t * 4]);
#pragma unroll
        for (int j = 0; j < 4; j++) {
          acc[u][j] += q4.x * kk[j][ts].x + q4.y * kk[j][ts].y
                     + q4.z * kk[j][ts].z + q4.w * kk[j][ts].w
                     + k4.x * qq[j][ts].x + k4.y * qq[j][ts].y
                     + k4.z * qq[j][ts].z + k4.w * qq[j][ts].w;
        }
      }
    }
  }
#pragma unroll
  for (int u = 0; u < UC; u++) {
    int row = rows_s[u];
#pragma unroll
    for (int j = 0; j < 4; j++) {
      int l = tid + j * 512;
      sc[u][l] = (l > row) ? -1e9f : acc[u][j] * 0.0625f;
    }
  }
  __syncthreads();

  // pass 2: softmax per u; wave w handles u=w (waves 0..4)
  int w = tid >> 6, lane = tid & 63;
  if (w < UC) {
    float mx = -INFINITY;
    for (int kq = 0; kq < 32; kq++) mx = fmaxf(mx, sc[w][lane + 64 * kq]);
    for (int off = 32; off; off >>= 1) mx = fmaxf(mx, __shfl_xor(mx, off, 64));
    float sum = 0.f;
    for (int kq = 0; kq < 32; kq++) {
      float e = __expf(sc[w][lane + 64 * kq] - mx);
      sc[w][lane + 64 * kq] = e;
      sum += e;
    }
    for (int off = 32; off; off >>= 1) sum += __shfl_xor(sum, off, 64);
    if (lane == 0) inv_s[w] = 1.0f / sum;
  }
  __syncthreads();

  // pass 3: attn @ V ; wave w owns l in [w*256, w*256+256) for ALL 5 u.
  {
    int quad = lane & 15, lr = lane >> 4;
    int l0w = w * 256;
    const float4* V4 = (const float4*)Vb;
    float4 a[UC];
#pragma unroll
    for (int u = 0; u < UC; u++) a[u] = make_float4(0.f, 0.f, 0.f, 0.f);
    for (int it4 = 0; it4 < 16; it4++) {
      int lb = l0w + lr + it4 * 16;
      float4 v0 = V4[(size_t)(lb)      * 16 + quad];
      float4 v1 = V4[(size_t)(lb + 4)  * 16 + quad];
      float4 v2 = V4[(size_t)(lb + 8)  * 16 + quad];
      float4 v3 = V4[(size_t)(lb + 12) * 16 + quad];
#pragma unroll
      for (int u = 0; u < UC; u++) {
        float s0 = sc[u][lb], s1 = sc[u][lb + 4], s2 = sc[u][lb + 8], s3 = sc[u][lb + 12];
        a[u].x += s0 * v0.x + s1 * v1.x + s2 * v2.x + s3 * v3.x;
        a[u].y += s0 * v0.y + s1 * v1.y + s2 * v2.y + s3 * v3.y;
        a[u].z += s0 * v0.z + s1 * v1.z + s2 * v2.z + s3 * v3.z;
        a[u].w += s0 * v0.w + s1 * v1.w + s2 * v2.w + s3 * v3.w;
      }
    }
#pragma unroll
    for (int u = 0; u < UC; u++) {
#pragma unroll
      for (int off = 16; off < 64; off <<= 1) {
        a[u].x += __shfl_xor(a[u].x, off, 64);
        a[u].y += __shfl_xor(a[u].y, off, 64);
        a[u].z += __shfl_xor(a[u].z, off, 64);
        a[u].w += __shfl_xor(a[u].w, off, 64);
      }
      if (lr == 0) *(float4*)(&redp[w][u][quad * 4]) = a[u];
    }
  }
  __syncthreads();

  if (w < UC) {
    float r = 0.f;
#pragma unroll
    for (int g = 0; g < 8; g++) r += redp[g][w][lane];
    float outv = 0.5f * (vs[w][lane] + r * inv_s[w]);
    int row = rows_s[w];
    out[(((size_t)b * Ln + row) * Hn + h) * Dn + lane] = outv;
  }
}

extern "C" void kernel_launch(void* const* d_in, const int* in_sizes, int n_in,
                              void* d_out, int out_size, void* d_ws, size_t ws_size,
                              hipStream_t stream) {
  const float* Q = (const float*)d_in[0];  // (B,L,H,D) flat == (B,H,L,D) reshape
  const float* K = (const float*)d_in[1];
  const float* V = (const float*)d_in[2];
  float* out = (float*)d_out;
  char* ws = (char*)d_ws;

  float* M       = (float*)(ws + NSAMP * 4);                       // 256 KB
  int*   Mtop    = (int*)(ws + NSAMP * 4 + BHn * Ln * 4);          // 5 KB
  float* partial = (float*)(ws + NSAMP * 4 + BHn * Ln * 4 + BHn * NTOP * 4); // 256 KB

  // Partitionable threefry split of key(42) = (0,42): k2 = tf(key, ctr=(0,1)).
  uint32_t s0 = 0u, s1 = 1u;
  tf2x32(0u, 42u, s0, s1);

  // 3 launches: {vsum || compute_M} -> topk_select -> {sparse_attn || context}
  fused_m_vsum<<<1024 + 8192, 256, 0, stream>>>(Q, K, V, M, partial, s0, s1);
  topk_select<<<BHn, 256, 0, stream>>>(M, Mtop);
  sparse_ctx<<<SPB + 256, 512, 0, stream>>>(Q, K, V, Mtop, partial, out);
}